// Round 2
// baseline (511.659 us; speedup 1.0000x reference)
//
#include <hip/hip_runtime.h>
#include <stdint.h>

#define CDIM 128
#define NNODES 100000
#define E0EDGES 300000
#define ELEDGES 80000

typedef unsigned short u16;
typedef unsigned int u32;
typedef short bf16x8 __attribute__((ext_vector_type(8)));
typedef float f32x4 __attribute__((ext_vector_type(4)));

__device__ __forceinline__ float bf2f(u32 u){
  union { u32 i; float f; } v; v.i = u << 16; return v.f;
}
__device__ __forceinline__ u16 f2bf(float f){
  u32 u = __builtin_bit_cast(u32, f);
  u32 r = (u + 0x7fffu + ((u >> 16) & 1u)) >> 16;
  return (u16)r;
}
__device__ __forceinline__ u32 pack2(float lo, float hi){
  return ((u32)f2bf(hi) << 16) | (u32)f2bf(lo);
}
// element index into a swizzled [rows][128] bf16 LDS tile (XOR chunk swizzle,
// 16B granules: chunk' = chunk ^ (row&7) -> 2-way max bank aliasing on b128 reads)
__device__ __forceinline__ int swzi(int r, int c){
  return r*CDIM + ((((c>>3) ^ (r&7)))<<3) + (c&7);
}

// 64x128x128 GEMM core: A [64][128] swizzled LDS (rows = wave*16+lane%16),
// B as B^T [col][k] swizzled LDS. MFMA 16x16x32 bf16, guide-verified layouts.
__device__ __forceinline__ void gemm64(const u16* A, const u16* B, f32x4* acc, int wave, int lane){
  const int lr = lane & 15, g = lane >> 4;
  const int arow = wave*16 + lr;
#pragma unroll
  for (int ks = 0; ks < 4; ++ks){
    const int ach = ks*4 + g;                 // 16B chunk index along k
    bf16x8 a = *(const bf16x8*)&A[arow*CDIM + ((ach ^ (arow & 7)) << 3)];
#pragma unroll
    for (int ct = 0; ct < 8; ++ct){
      const int brow = ct*16 + lr;
      bf16x8 b = *(const bf16x8*)&B[brow*CDIM + ((ach ^ (brow & 7)) << 3)];
      acc[ct] = __builtin_amdgcn_mfma_f32_16x16x32_bf16(a, b, acc[ct], 0, 0, 0);
    }
  }
}

// stage a [128][128] bf16 (pre-converted, B^T row-major) matrix into swizzled LDS
__device__ __forceinline__ void stage_w(const u16* __restrict__ gsrc, u16* sdst, int tid){
  for (int c = tid; c < CDIM*16; c += 256){
    int r = c >> 4, ch = c & 15;
    *(uint4*)&sdst[(r*16 + (ch ^ (r & 7)))*8] = ((const uint4*)(gsrc + r*CDIM))[ch];
  }
}

// ---------------- prep: f32->bf16 transpose weights to B^T + eWt = emb@Wt_bot + bt (f32)
__global__ __launch_bounds__(256) void prep_kernel(
    const float* __restrict__ Wt, const float* __restrict__ w0, const float* __restrict__ w1,
    const float* __restrict__ fw0, const float* __restrict__ fw1,
    const float* __restrict__ emb, const float* __restrict__ bt,
    u16* __restrict__ WtT, u16* __restrict__ w0T, u16* __restrict__ w1T,
    u16* __restrict__ fw0T, u16* __restrict__ fw1T, float* __restrict__ eWt)
{
  int tid = blockIdx.x*blockDim.x + threadIdx.x;
  int nt = gridDim.x*blockDim.x;
  for (int idx = tid; idx < 3*CDIM*CDIM; idx += nt){
    int i = idx/(CDIM*CDIM), rem = idx%(CDIM*CDIM), col = rem/CDIM, k = rem%CDIM;
    WtT[idx] = f2bf(Wt[(size_t)i*2*CDIM*CDIM + k*CDIM + col]);   // top half of Wt
    w0T[idx] = f2bf(w0[(size_t)i*CDIM*CDIM + k*CDIM + col]);
    w1T[idx] = f2bf(w1[(size_t)i*CDIM*CDIM + k*CDIM + col]);
  }
  for (int idx = tid; idx < CDIM*CDIM; idx += nt){
    int col = idx/CDIM, k = idx%CDIM;
    fw0T[idx] = f2bf(fw0[k*CDIM + col]);
    fw1T[idx] = f2bf(fw1[k*CDIM + col]);
  }
  for (int idx = tid; idx < 3*3*CDIM; idx += nt){
    int i = idx/(3*CDIM), a = (idx/CDIM)%3, c2 = idx%CDIM;
    float s = bt[i*CDIM + c2];
    for (int k = 0; k < CDIM; ++k)
      s += emb[(i*3 + a)*CDIM + k] * Wt[(size_t)i*2*CDIM*CDIM + (CDIM + k)*CDIM + c2];
    eWt[idx] = s;
  }
}

// ---------------- CSR rowptr from sorted target list (edge-parallel, no search)
__global__ __launch_bounds__(256) void build_csr_kernel(
    const int* __restrict__ tgt, int ne, int* __restrict__ rowptr)
{
  int e = blockIdx.x*blockDim.x + threadIdx.x;
  if (e >= ne) return;
  int tc = tgt[e];
  int tp = (e == 0) ? -1 : tgt[e-1];
  for (int n = tp + 1; n <= tc; ++n) rowptr[n] = e;
  if (e == ne - 1){
    for (int n = tc + 1; n <= NNODES; ++n) rowptr[n] = ne;
  }
}

// ---------------- layer kernel: per block TE edges x (L+1) positions (padded RPE rows)
template<int L>
__global__ __launch_bounds__(256) void layer_kernel(
    const float* __restrict__ x,
    const int* __restrict__ nl,      // (L+2, EL): row0 tgt, rows 1..L+1 sources
    const int* __restrict__ ai,      // (L+2, EL)
    const u16* __restrict__ WtT, const u16* __restrict__ w0T, const u16* __restrict__ w1T,
    const float* __restrict__ eWt,   // (3,3,C) f32
    const float* __restrict__ b0g, const float* __restrict__ b1g,
    const float* __restrict__ cepsg,
    u16* __restrict__ oL)            // (EL, C) per-edge output (bf16)
{
  constexpr int RPE = (L == 1) ? 2 : 4;   // rows per edge (L=2 padded with dummy)
  constexpr int TE  = 64 / RPE;
  constexpr int LI  = L - 1;
  __shared__ __align__(16) u16 sW[CDIM*CDIM];   // weights (B^T, swizzled); rows 0..63 reused as h buffer
  __shared__ __align__(16) u16 sA[64*CDIM];     // cc -> z -> t (swizzled)
  __shared__ int sNode[64];
  __shared__ int sAid[64];
  u16* sH = sW;

  const int tid  = threadIdx.x;
  const int e0   = blockIdx.x * TE;
  const int wave = tid >> 6, lane = tid & 63;
  const int lr   = lane & 15, g = lane >> 4;

  if (tid < 64){
    int r = tid, ed = e0 + r / RPE, pos = r % RPE;
    int node = -1, a = 0;
    if (pos <= L && ed < ELEDGES){
      node = nl[(1 + pos)*ELEDGES + ed];
      a    = ai[(1 + pos)*ELEDGES + ed];
    }
    sNode[r] = node; sAid[r] = a;
  }
  stage_w(WtT + LI*CDIM*CDIM, sW, tid);
  __syncthreads();
  // gather cc rows (f32 -> bf16)
  for (int c = tid; c < 64*16; c += 256){
    int r = c >> 4, ch = c & 15;
    int node = sNode[r];
    uint4 v = make_uint4(0u,0u,0u,0u);
    if (node >= 0){
      const float4* px = (const float4*)(x + (size_t)node*CDIM + ch*8);
      float4 fa = px[0], fb = px[1];
      v.x = pack2(fa.x, fa.y); v.y = pack2(fa.z, fa.w);
      v.z = pack2(fb.x, fb.y); v.w = pack2(fb.z, fb.w);
    }
    *(uint4*)&sA[(r*16 + (ch ^ (r & 7)))*8] = v;
  }
  __syncthreads();

  f32x4 acc[8];
#pragma unroll
  for (int ct = 0; ct < 8; ++ct) acc[ct] = (f32x4){0.f,0.f,0.f,0.f};
  gemm64(sA, sW, acc, wave, lane);        // GEMM1: cc @ Wt_top
  __syncthreads();                        // all B-reads of sW done -> h may overwrite
  // epilogue1: h = acc + eWt[aid]  -> sH (= sW rows 0..63)
#pragma unroll
  for (int ct = 0; ct < 8; ++ct){
    const int col = ct*16 + lr;
#pragma unroll
    for (int q = 0; q < 4; ++q){
      const int r = wave*16 + g*4 + q;
      float h = acc[ct][q] + eWt[(LI*3 + sAid[r])*CDIM + col];
      sH[swzi(r, col)] = f2bf(h);
    }
  }
  __syncthreads();
  // z = (1+ce)*cc + h[r-1] + h[r+1]  (within-edge stencil), in place in sA
  {
    const float ce = 1.0f + cepsg[LI];
    for (int c = tid; c < 64*16; c += 256){
      int r = c >> 4, ch = c & 15;
      int pos = r & (RPE - 1);
      uint4 cc = *(const uint4*)&sA[(r*16 + (ch ^ (r & 7)))*8];
      uint4 hm = make_uint4(0,0,0,0), hp = make_uint4(0,0,0,0);
      if (pos > 0) hm = *(const uint4*)&sH[((r-1)*16 + (ch ^ ((r-1) & 7)))*8];
      if (pos < L) hp = *(const uint4*)&sH[((r+1)*16 + (ch ^ ((r+1) & 7)))*8];
      uint4 z;
      u32* pc = (u32*)&cc; u32* pm = (u32*)&hm; u32* pp = (u32*)&hp; u32* pz = (u32*)&z;
#pragma unroll
      for (int j = 0; j < 4; ++j){
        float zlo = ce*bf2f(pc[j] & 0xffffu) + bf2f(pm[j] & 0xffffu) + bf2f(pp[j] & 0xffffu);
        float zhi = ce*bf2f(pc[j] >> 16)     + bf2f(pm[j] >> 16)     + bf2f(pp[j] >> 16);
        pz[j] = pack2(zlo, zhi);
      }
      *(uint4*)&sA[(r*16 + (ch ^ (r & 7)))*8] = z;
    }
  }
  __syncthreads();
  stage_w(w0T + LI*CDIM*CDIM, sW, tid);
  __syncthreads();

#pragma unroll
  for (int ct = 0; ct < 8; ++ct) acc[ct] = (f32x4){0.f,0.f,0.f,0.f};
  gemm64(sA, sW, acc, wave, lane);        // GEMM2: z @ w0
  __syncthreads();                        // sW reads done -> restage; sA reads are own-wave only
  // epilogue2: t = relu(acc + b0) -> sA ; stage w1 in parallel
#pragma unroll
  for (int ct = 0; ct < 8; ++ct){
    const int col = ct*16 + lr;
    const float bb = b0g[LI*CDIM + col];
#pragma unroll
    for (int q = 0; q < 4; ++q){
      const int r = wave*16 + g*4 + q;
      float t = acc[ct][q] + bb;
      t = t > 0.f ? t : 0.f;
      sA[swzi(r, col)] = f2bf(t);
    }
  }
  stage_w(w1T + LI*CDIM*CDIM, sW, tid);
  __syncthreads();

#pragma unroll
  for (int ct = 0; ct < 8; ++ct) acc[ct] = (f32x4){0.f,0.f,0.f,0.f};
  gemm64(sA, sW, acc, wave, lane);        // GEMM3: t @ w1
  // epilogue3: per-edge position sums are lane-local (rows of an edge = one lane-group's 4 regs)
#pragma unroll
  for (int ct = 0; ct < 8; ++ct){
    const int col = ct*16 + lr;
    const float bb = b1g[LI*CDIM + col];
    if (L == 1){
      float oa = acc[ct][0] + acc[ct][1] + 2.f*bb;
      float ob = acc[ct][2] + acc[ct][3] + 2.f*bb;
      int ea = e0 + wave*8 + 2*g;
      oL[(size_t)ea*CDIM + col]     = f2bf(oa);
      oL[(size_t)(ea+1)*CDIM + col] = f2bf(ob);
    } else if (L == 2){
      float ov = acc[ct][0] + acc[ct][1] + acc[ct][2] + 3.f*bb;   // q=3 is dummy row
      int e = e0 + wave*4 + g;
      oL[(size_t)e*CDIM + col] = f2bf(ov);
    } else {
      float ov = acc[ct][0] + acc[ct][1] + acc[ct][2] + acc[ct][3] + 4.f*bb;
      int e = e0 + wave*4 + g;
      oL[(size_t)e*CDIM + col] = f2bf(ov);
    }
  }
}

// ---------------- per-node gather: rc = (1+r0)*seg0 + sum_L (1+rL)*segL  (bf16 out)
__global__ __launch_bounds__(256) void gather_rc_kernel(
    const float* __restrict__ x,
    const int* __restrict__ s0,       // loopyN0 row 1 (sources)
    const int* __restrict__ rp0, const int* __restrict__ rp1,
    const int* __restrict__ rp2, const int* __restrict__ rp3,
    const u16* __restrict__ o1, const u16* __restrict__ o2, const u16* __restrict__ o3,
    const float* __restrict__ repsg, u16* __restrict__ rcb)
{
  const int wave = threadIdx.x >> 6, lane = threadIdx.x & 63;
  const int node = blockIdx.x*4 + wave;
  if (node >= NNODES) return;
  float a0 = 0.f, a1 = 0.f;
  {
    const float sc = 1.f + repsg[0];
    int lo = rp0[node], hi = rp0[node+1];
    for (int e = lo; e < hi; ++e){
      int s = s0[e];
      float2 v = *(const float2*)(x + (size_t)s*CDIM + lane*2);
      a0 += sc*v.x; a1 += sc*v.y;
    }
  }
  const u16* os[3]  = {o1, o2, o3};
  const int* rps[3] = {rp1, rp2, rp3};
#pragma unroll
  for (int li = 0; li < 3; ++li){
    const float sc = 1.f + repsg[1+li];
    int lo = rps[li][node], hi = rps[li][node+1];
    for (int e = lo; e < hi; ++e){
      u32 v = *(const u32*)(os[li] + (size_t)e*CDIM + lane*2);
      a0 += sc*bf2f(v & 0xffffu); a1 += sc*bf2f(v >> 16);
    }
  }
  *(u32*)(rcb + (size_t)node*CDIM + lane*2) = pack2(a0, a1);
}

// ---------------- final: out = mlp2((1+eps)*x + rc, fin_*)  (f32 out)
__global__ __launch_bounds__(256) void final_kernel(
    const float* __restrict__ x, const u16* __restrict__ rc,
    const u16* __restrict__ fw0T, const u16* __restrict__ fw1T,
    const float* __restrict__ fb0, const float* __restrict__ fb1,
    const float* __restrict__ epsg, float* __restrict__ outp)
{
  __shared__ __align__(16) u16 sW[CDIM*CDIM];
  __shared__ __align__(16) u16 sA[64*CDIM];
  const int tid  = threadIdx.x;
  const int wave = tid >> 6, lane = tid & 63;
  const int lr   = lane & 15, g = lane >> 4;
  const int r0   = blockIdx.x * 64;
  const float se = 1.0f + epsg[0];

  stage_w(fw0T, sW, tid);
  for (int c = tid; c < 64*16; c += 256){
    int r = c >> 4, ch = c & 15;
    int node = r0 + r;
    uint4 v = make_uint4(0,0,0,0);
    if (node < NNODES){
      const float4* px = (const float4*)(x + (size_t)node*CDIM + ch*8);
      float4 fa = px[0], fb = px[1];
      const u32* pr = (const u32*)(rc + (size_t)node*CDIM + ch*8);
      u32 r0v = pr[0], r1v = pr[1], r2v = pr[2], r3v = pr[3];
      v.x = pack2(se*fa.x + bf2f(r0v & 0xffffu), se*fa.y + bf2f(r0v >> 16));
      v.y = pack2(se*fa.z + bf2f(r1v & 0xffffu), se*fa.w + bf2f(r1v >> 16));
      v.z = pack2(se*fb.x + bf2f(r2v & 0xffffu), se*fb.y + bf2f(r2v >> 16));
      v.w = pack2(se*fb.z + bf2f(r3v & 0xffffu), se*fb.w + bf2f(r3v >> 16));
    }
    *(uint4*)&sA[(r*16 + (ch ^ (r & 7)))*8] = v;
  }
  __syncthreads();

  f32x4 acc[8];
#pragma unroll
  for (int ct = 0; ct < 8; ++ct) acc[ct] = (f32x4){0.f,0.f,0.f,0.f};
  gemm64(sA, sW, acc, wave, lane);
  __syncthreads();
#pragma unroll
  for (int ct = 0; ct < 8; ++ct){
    const int col = ct*16 + lr;
    const float bb = fb0[col];
#pragma unroll
    for (int q = 0; q < 4; ++q){
      const int r = wave*16 + g*4 + q;
      float t = acc[ct][q] + bb;
      t = t > 0.f ? t : 0.f;
      sA[swzi(r, col)] = f2bf(t);
    }
  }
  stage_w(fw1T, sW, tid);
  __syncthreads();
#pragma unroll
  for (int ct = 0; ct < 8; ++ct) acc[ct] = (f32x4){0.f,0.f,0.f,0.f};
  gemm64(sA, sW, acc, wave, lane);
#pragma unroll
  for (int ct = 0; ct < 8; ++ct){
    const int col = ct*16 + lr;
    const float bb = fb1[col];
#pragma unroll
    for (int q = 0; q < 4; ++q){
      const int r = wave*16 + g*4 + q;
      int node = r0 + r;
      if (node < NNODES) outp[(size_t)node*CDIM + col] = acc[ct][q] + bb;
    }
  }
}

extern "C" void kernel_launch(void* const* d_in, const int* in_sizes, int n_in,
                              void* d_out, int out_size, void* d_ws, size_t ws_size,
                              hipStream_t stream)
{
  const float* x   = (const float*)d_in[0];
  const int* n0    = (const int*)d_in[1];
  const int* n1    = (const int*)d_in[2];
  const int* a1    = (const int*)d_in[3];
  const int* n2    = (const int*)d_in[4];
  const int* a2    = (const int*)d_in[5];
  const int* n3    = (const int*)d_in[6];
  const int* a3    = (const int*)d_in[7];
  const float* emb = (const float*)d_in[8];
  const float* Wt  = (const float*)d_in[9];
  const float* bt  = (const float*)d_in[10];
  const float* w0  = (const float*)d_in[11];
  const float* b0  = (const float*)d_in[12];
  const float* w1  = (const float*)d_in[13];
  const float* b1  = (const float*)d_in[14];
  const float* ceps= (const float*)d_in[15];
  const float* reps= (const float*)d_in[16];
  const float* eps = (const float*)d_in[17];
  const float* fw0 = (const float*)d_in[18];
  const float* fb0 = (const float*)d_in[19];
  const float* fw1 = (const float*)d_in[20];
  const float* fb1 = (const float*)d_in[21];
  float* outp = (float*)d_out;

  char* w = (char*)d_ws;
  size_t off = 0;
  auto alloc = [&](size_t bytes) -> char* {
    char* p = w + off;
    off += (bytes + 255) & ~((size_t)255);
    return p;
  };
  u16* o1   = (u16*)alloc((size_t)ELEDGES*CDIM*2);
  u16* o2   = (u16*)alloc((size_t)ELEDGES*CDIM*2);
  u16* o3   = (u16*)alloc((size_t)ELEDGES*CDIM*2);
  u16* rcb  = (u16*)alloc((size_t)NNODES*CDIM*2);
  int* rp0  = (int*)alloc((size_t)(NNODES+1)*4);
  int* rp1  = (int*)alloc((size_t)(NNODES+1)*4);
  int* rp2  = (int*)alloc((size_t)(NNODES+1)*4);
  int* rp3  = (int*)alloc((size_t)(NNODES+1)*4);
  u16* WtT  = (u16*)alloc((size_t)3*CDIM*CDIM*2);
  u16* w0T  = (u16*)alloc((size_t)3*CDIM*CDIM*2);
  u16* w1T  = (u16*)alloc((size_t)3*CDIM*CDIM*2);
  u16* fw0T = (u16*)alloc((size_t)CDIM*CDIM*2);
  u16* fw1T = (u16*)alloc((size_t)CDIM*CDIM*2);
  float* eWt = (float*)alloc((size_t)3*3*CDIM*4);
  (void)ws_size; (void)in_sizes; (void)n_in; (void)out_size;

  prep_kernel<<<192, 256, 0, stream>>>(Wt, w0, w1, fw0, fw1, emb, bt,
                                       WtT, w0T, w1T, fw0T, fw1T, eWt);
  build_csr_kernel<<<(E0EDGES+255)/256, 256, 0, stream>>>(n0, E0EDGES, rp0);
  build_csr_kernel<<<(ELEDGES+255)/256, 256, 0, stream>>>(n1, ELEDGES, rp1);
  build_csr_kernel<<<(ELEDGES+255)/256, 256, 0, stream>>>(n2, ELEDGES, rp2);
  build_csr_kernel<<<(ELEDGES+255)/256, 256, 0, stream>>>(n3, ELEDGES, rp3);

  layer_kernel<1><<<ELEDGES/32, 256, 0, stream>>>(x, n1, a1, WtT, w0T, w1T, eWt, b0, b1, ceps, o1);
  layer_kernel<2><<<ELEDGES/16, 256, 0, stream>>>(x, n2, a2, WtT, w0T, w1T, eWt, b0, b1, ceps, o2);
  layer_kernel<3><<<ELEDGES/16, 256, 0, stream>>>(x, n3, a3, WtT, w0T, w1T, eWt, b0, b1, ceps, o3);

  gather_rc_kernel<<<(NNODES+3)/4, 256, 0, stream>>>(x, n0 + E0EDGES, rp0, rp1, rp2, rp3,
                                                     o1, o2, o3, reps, rcb);
  final_kernel<<<(NNODES+63)/64, 256, 0, stream>>>(x, rcb, fw0T, fw1T, fb0, fb1, eps, outp);
}

// Round 3
// 436.622 us; speedup vs baseline: 1.1719x; 1.1719x over previous
//
#include <hip/hip_runtime.h>
#include <stdint.h>

#define CDIM 128
#define NNODES 100000
#define E0EDGES 300000
#define ELEDGES 80000

typedef unsigned short u16;
typedef unsigned int u32;
typedef short bf16x8 __attribute__((ext_vector_type(8)));
typedef float f32x4 __attribute__((ext_vector_type(4)));

__device__ __forceinline__ float bf2f(u32 u){
  union { u32 i; float f; } v; v.i = u << 16; return v.f;
}
__device__ __forceinline__ float bf2f_hi(u32 u){
  union { u32 i; float f; } v; v.i = u & 0xffff0000u; return v.f;
}
__device__ __forceinline__ u16 f2bf(float f){
  u32 u = __builtin_bit_cast(u32, f);
  u32 r = (u + 0x7fffu + ((u >> 16) & 1u)) >> 16;
  return (u16)r;
}
__device__ __forceinline__ u32 pack2(float lo, float hi){
  return ((u32)f2bf(hi) << 16) | (u32)f2bf(lo);
}
// HW packed f32->bf16 (RNE), 1 instr for 2 elements
__device__ __forceinline__ u32 cvtpk(float lo, float hi){
  u32 r;
  asm("v_cvt_pk_bf16_f32 %0, %1, %2" : "=v"(r) : "v"(lo), "v"(hi));
  return r;
}
// DPP cross-lane move (0-fill at row boundary)
template<int CTRL>
__device__ __forceinline__ float dppf(float v){
  int r = __builtin_amdgcn_update_dpp(0, __builtin_bit_cast(int, v), CTRL, 0xF, 0xF, true);
  return __builtin_bit_cast(float, r);
}
#define DPP_SHR1 0x111   // lane l <- l-1 (within 16-lane row)
#define DPP_SHL1 0x101   // lane l <- l+1
#define DPP_XOR1 0xB1    // quad_perm [1,0,3,2]
#define DPP_XOR2 0x4E    // quad_perm [2,3,0,1]

// element index of swizzled [rows][128] bf16 LDS tile (16B-granule XOR swizzle)
__device__ __forceinline__ int swzi(int r, int c){
  return r*CDIM + ((((c>>3) ^ (r&7)))<<3) + (c&7);
}
// index of a 4-col group (col0 multiple of 4, stays within one 8-col granule)
__device__ __forceinline__ int swz8(int r, int col0){
  int chunk = col0 >> 3;
  return r*CDIM + ((chunk ^ (r & 7)) << 3) + (col0 & 7);
}

// ---- original gemm: acc(row = g*4+q, col = ct*16+lr); A=activations, B=weights
__device__ __forceinline__ void gemm64(const u16* A, const u16* B, f32x4* acc, int wave, int lane){
  const int lr = lane & 15, g = lane >> 4;
  const int arow = wave*16 + lr;
#pragma unroll
  for (int ks = 0; ks < 4; ++ks){
    const int ach = ks*4 + g;
    bf16x8 a = *(const bf16x8*)&A[arow*CDIM + ((ach ^ (arow & 7)) << 3)];
#pragma unroll
    for (int ct = 0; ct < 8; ++ct){
      const int brow = ct*16 + lr;
      bf16x8 b = *(const bf16x8*)&B[brow*CDIM + ((ach ^ (brow & 7)) << 3)];
      acc[ct] = __builtin_amdgcn_mfma_f32_16x16x32_bf16(a, b, acc[ct], 0, 0, 0);
    }
  }
}

// ---- swapped gemm: first operand = weights -> acc(row = lane&15, cols = ct*16+g*4+q)
__device__ __forceinline__ void gemmS(const u16* W, const u16* Z, f32x4* acc, int zrow, int lane){
  const int lr = lane & 15, g = lane >> 4;
#pragma unroll
  for (int ks = 0; ks < 4; ++ks){
    const int ch = ks*4 + g;
    bf16x8 zb = *(const bf16x8*)&Z[zrow*CDIM + ((ch ^ (zrow & 7)) << 3)];
#pragma unroll
    for (int ct = 0; ct < 8; ++ct){
      const int wrow = ct*16 + lr;
      bf16x8 wb = *(const bf16x8*)&W[wrow*CDIM + ((ch ^ (wrow & 7)) << 3)];
      acc[ct] = __builtin_amdgcn_mfma_f32_16x16x32_bf16(wb, zb, acc[ct], 0, 0, 0);
    }
  }
}

// stage a [128][128] bf16 (B^T row-major) matrix into swizzled LDS (256 threads)
__device__ __forceinline__ void stage_w(const u16* __restrict__ gsrc, u16* sdst, int tid){
  for (int c = tid; c < CDIM*16; c += 256){
    int r = c >> 4, ch = c & 15;
    *(uint4*)&sdst[(r*16 + (ch ^ (r & 7)))*8] = ((const uint4*)(gsrc + r*CDIM))[ch];
  }
}

// ---------------- xb: bf16 copy of x
__global__ __launch_bounds__(256) void xb_kernel(const float* __restrict__ x, u16* __restrict__ xb){
  int i = blockIdx.x*256 + threadIdx.x;
  size_t idx = (size_t)i*4;
  if (idx < (size_t)NNODES*CDIM){
    float4 v = *(const float4*)(x + idx);
    uint2 o; o.x = cvtpk(v.x, v.y); o.y = cvtpk(v.z, v.w);
    *(uint2*)(xb + idx) = o;
  }
}

// ---------------- prep: f32->bf16 transpose weights to B^T + eWt = emb@Wt_bot + bt (f32)
__global__ __launch_bounds__(256) void prep_kernel(
    const float* __restrict__ Wt, const float* __restrict__ w0, const float* __restrict__ w1,
    const float* __restrict__ fw0, const float* __restrict__ fw1,
    const float* __restrict__ emb, const float* __restrict__ bt,
    u16* __restrict__ WtT, u16* __restrict__ w0T, u16* __restrict__ w1T,
    u16* __restrict__ fw0T, u16* __restrict__ fw1T, float* __restrict__ eWt)
{
  int tid = blockIdx.x*blockDim.x + threadIdx.x;
  int nt = gridDim.x*blockDim.x;
  for (int idx = tid; idx < 3*CDIM*CDIM; idx += nt){
    int i = idx/(CDIM*CDIM), rem = idx%(CDIM*CDIM), col = rem/CDIM, k = rem%CDIM;
    WtT[idx] = f2bf(Wt[(size_t)i*2*CDIM*CDIM + k*CDIM + col]);   // top half of Wt
    w0T[idx] = f2bf(w0[(size_t)i*CDIM*CDIM + k*CDIM + col]);
    w1T[idx] = f2bf(w1[(size_t)i*CDIM*CDIM + k*CDIM + col]);
  }
  for (int idx = tid; idx < CDIM*CDIM; idx += nt){
    int col = idx/CDIM, k = idx%CDIM;
    fw0T[idx] = f2bf(fw0[k*CDIM + col]);
    fw1T[idx] = f2bf(fw1[k*CDIM + col]);
  }
  for (int idx = tid; idx < 3*3*CDIM; idx += nt){
    int i = idx/(3*CDIM), a = (idx/CDIM)%3, c2 = idx%CDIM;
    float s = bt[i*CDIM + c2];
    for (int k = 0; k < CDIM; ++k)
      s += emb[(i*3 + a)*CDIM + k] * Wt[(size_t)i*2*CDIM*CDIM + (CDIM + k)*CDIM + c2];
    eWt[idx] = s;
  }
}

// ---------------- CSR rowptr from sorted target list
__global__ __launch_bounds__(256) void build_csr_kernel(
    const int* __restrict__ tgt, int ne, int* __restrict__ rowptr)
{
  int e = blockIdx.x*blockDim.x + threadIdx.x;
  if (e >= ne) return;
  int tc = tgt[e];
  int tp = (e == 0) ? -1 : tgt[e-1];
  for (int n = tp + 1; n <= tc; ++n) rowptr[n] = e;
  if (e == ne - 1){
    for (int n = tc + 1; n <= NNODES; ++n) rowptr[n] = ne;
  }
}

// ---------------- layer kernel: 512 threads, 128 rows (TE edges x RPE positions)
// swapped-MFMA layout: acc(row = wave*16 + lane&15, cols = ct*16 + g*4 + q)
template<int L>
__global__ __launch_bounds__(512, 4) void layer_kernel(
    const u16* __restrict__ xb,
    const int* __restrict__ nl,      // (L+2, EL)
    const int* __restrict__ ai,      // (L+2, EL)
    const u16* __restrict__ WtT, const u16* __restrict__ w0T, const u16* __restrict__ w1T,
    const float* __restrict__ eWt,   // (3,3,128) f32
    const float* __restrict__ b0g, const float* __restrict__ b1g,
    const float* __restrict__ cepsg,
    u16* __restrict__ oL)            // (EL, 128) bf16
{
  constexpr int RPE = (L == 1) ? 2 : 4;
  constexpr int TE  = 128 / RPE;
  constexpr int LI  = L - 1;
  __shared__ __align__(16) u16 sW[CDIM*CDIM];     // 32 KB weights
  __shared__ __align__(16) u16 sA[128*CDIM];      // 32 KB activations (wave-private rows)
  __shared__ __align__(16) float sE[3*136];       // eWt slice, padded stride vs bank clash
  __shared__ __align__(16) float b0s[CDIM];
  __shared__ __align__(16) float b1s[CDIM];

  const int tid  = threadIdx.x;
  const int wave = tid >> 6, lane = tid & 63;
  const int lr   = lane & 15, g = lane >> 4;
  const int row  = wave*16 + lr;                  // this lane's activation row
  const int e0   = blockIdx.x * TE;
  const int ed   = e0 + row / RPE;
  const int pos  = row % RPE;

  int node = -1, aid = 0;
  if (pos <= L){
    node = nl[(1 + pos)*ELEDGES + ed];
    aid  = ai[(1 + pos)*ELEDGES + ed];
  }
  const float mu = (pos > 0) ? 1.f : 0.f;         // stencil up-mask
  const float md = (pos < L) ? 1.f : 0.f;         // stencil down-mask
  const float ce = 1.0f + cepsg[LI];

  // stage Wt (all threads)
  for (int c = tid; c < CDIM*16; c += 512){
    int r = c >> 4, ch = c & 15;
    *(uint4*)&sW[(r*16 + (ch ^ (r & 7)))*8] = ((const uint4*)(WtT + LI*CDIM*CDIM + r*CDIM))[ch];
  }
  for (int c = tid; c < 3*CDIM; c += 512) sE[(c>>7)*136 + (c&127)] = eWt[LI*3*CDIM + c];
  if (tid < CDIM) b0s[tid] = b0g[LI*CDIM + tid];
  else if (tid < 2*CDIM) b1s[tid-CDIM] = b1g[LI*CDIM + (tid-CDIM)];

  // gather own row (wave-private: no barrier needed vs GEMM1)
  {
    const uint4* src = (const uint4*)(xb + (size_t)(node < 0 ? 0 : node)*CDIM);
#pragma unroll
    for (int i2 = 0; i2 < 4; ++i2){
      int ch = g*4 + i2;
      uint4 v = make_uint4(0u,0u,0u,0u);
      if (node >= 0) v = src[ch];
      *(uint4*)&sA[(row*16 + (ch ^ (row & 7)))*8] = v;
    }
  }
  __syncthreads();                                 // B1: sW/sE ready

  f32x4 acc[8];
#pragma unroll
  for (int ct = 0; ct < 8; ++ct) acc[ct] = (f32x4){0.f,0.f,0.f,0.f};
  gemmS(sW, sA, acc, row, lane);                   // GEMM1: h-pre = cc @ Wt_top

  // epilogue1: h = acc + eWt[aid]; z = ce*cc + h[row-1] + h[row+1]; write z (in regs + DPP)
  {
    const float* eWrow = &sE[aid*136];
#pragma unroll
    for (int ct = 0; ct < 8; ++ct){
      const int col0 = ct*16 + g*4;
      float4 ew = *(const float4*)&eWrow[col0];
      float h0 = acc[ct][0] + ew.x;
      float h1 = acc[ct][1] + ew.y;
      float h2 = acc[ct][2] + ew.z;
      float h3 = acc[ct][3] + ew.w;
      float u0 = dppf<DPP_SHR1>(h0), u1 = dppf<DPP_SHR1>(h1),
            u2 = dppf<DPP_SHR1>(h2), u3 = dppf<DPP_SHR1>(h3);
      float d0 = dppf<DPP_SHL1>(h0), d1 = dppf<DPP_SHL1>(h1),
            d2 = dppf<DPP_SHL1>(h2), d3 = dppf<DPP_SHL1>(h3);
      uint2 ccv = *(const uint2*)&sA[swz8(row, col0)];
      float c0 = bf2f(ccv.x & 0xffffu), c1 = bf2f_hi(ccv.x);
      float c2 = bf2f(ccv.y & 0xffffu), c3 = bf2f_hi(ccv.y);
      float z0 = ce*c0 + mu*u0 + md*d0;
      float z1 = ce*c1 + mu*u1 + md*d1;
      float z2 = ce*c2 + mu*u2 + md*d2;
      float z3 = ce*c3 + mu*u3 + md*d3;
      uint2 zv; zv.x = cvtpk(z0, z1); zv.y = cvtpk(z2, z3);
      *(uint2*)&sA[swz8(row, col0)] = zv;
    }
  }
  __syncthreads();                                 // B2: all waves done reading sW(Wt)
  for (int c = tid; c < CDIM*16; c += 512){
    int r = c >> 4, ch = c & 15;
    *(uint4*)&sW[(r*16 + (ch ^ (r & 7)))*8] = ((const uint4*)(w0T + LI*CDIM*CDIM + r*CDIM))[ch];
  }
  __syncthreads();                                 // B3: sW = w0

#pragma unroll
  for (int ct = 0; ct < 8; ++ct) acc[ct] = (f32x4){0.f,0.f,0.f,0.f};
  gemmS(sW, sA, acc, row, lane);                   // GEMM2: z @ w0

  // epilogue2: t = relu(acc + b0) -> sA (own rows)
#pragma unroll
  for (int ct = 0; ct < 8; ++ct){
    const int col0 = ct*16 + g*4;
    float4 bb = *(const float4*)&b0s[col0];
    float t0 = acc[ct][0] + bb.x; t0 = t0 > 0.f ? t0 : 0.f;
    float t1 = acc[ct][1] + bb.y; t1 = t1 > 0.f ? t1 : 0.f;
    float t2 = acc[ct][2] + bb.z; t2 = t2 > 0.f ? t2 : 0.f;
    float t3 = acc[ct][3] + bb.w; t3 = t3 > 0.f ? t3 : 0.f;
    uint2 tv; tv.x = cvtpk(t0, t1); tv.y = cvtpk(t2, t3);
    *(uint2*)&sA[swz8(row, col0)] = tv;
  }
  __syncthreads();                                 // B4: all waves done reading sW(w0)
  for (int c = tid; c < CDIM*16; c += 512){
    int r = c >> 4, ch = c & 15;
    *(uint4*)&sW[(r*16 + (ch ^ (r & 7)))*8] = ((const uint4*)(w1T + LI*CDIM*CDIM + r*CDIM))[ch];
  }
  __syncthreads();                                 // B5: sW = w1

#pragma unroll
  for (int ct = 0; ct < 8; ++ct) acc[ct] = (f32x4){0.f,0.f,0.f,0.f};
  gemmS(sW, sA, acc, row, lane);                   // GEMM3: t @ w1

  // epilogue3: per-edge sum over positions (cross-lane quad reduce) + (L+1)*b1, store bf16
  const float mz = (L == 2 && pos == 3) ? 0.f : 1.f;
#pragma unroll
  for (int ct = 0; ct < 8; ++ct){
    const int col0 = ct*16 + g*4;
    float v0 = mz*acc[ct][0], v1 = mz*acc[ct][1], v2 = mz*acc[ct][2], v3 = mz*acc[ct][3];
    v0 += dppf<DPP_XOR1>(v0); v1 += dppf<DPP_XOR1>(v1);
    v2 += dppf<DPP_XOR1>(v2); v3 += dppf<DPP_XOR1>(v3);
    if constexpr (RPE == 4){
      v0 += dppf<DPP_XOR2>(v0); v1 += dppf<DPP_XOR2>(v1);
      v2 += dppf<DPP_XOR2>(v2); v3 += dppf<DPP_XOR2>(v3);
    }
    if (pos == 0){
      float4 bb = *(const float4*)&b1s[col0];
      const float nb = (float)(L + 1);
      uint2 ov;
      ov.x = cvtpk(v0 + nb*bb.x, v1 + nb*bb.y);
      ov.y = cvtpk(v2 + nb*bb.z, v3 + nb*bb.w);
      *(uint2*)(oL + (size_t)ed*CDIM + col0) = ov;
    }
  }
}

// ---------------- per-node gather: rc = (1+r0)*seg0 + sum_L (1+rL)*segL  (bf16 out)
__global__ __launch_bounds__(256) void gather_rc_kernel(
    const float* __restrict__ x,
    const int* __restrict__ s0,
    const int* __restrict__ rp0, const int* __restrict__ rp1,
    const int* __restrict__ rp2, const int* __restrict__ rp3,
    const u16* __restrict__ o1, const u16* __restrict__ o2, const u16* __restrict__ o3,
    const float* __restrict__ repsg, u16* __restrict__ rcb)
{
  const int wave = threadIdx.x >> 6, lane = threadIdx.x & 63;
  const int node = blockIdx.x*4 + wave;
  if (node >= NNODES) return;
  float a0 = 0.f, a1 = 0.f;
  {
    const float sc = 1.f + repsg[0];
    int lo = rp0[node], hi = rp0[node+1];
    for (int e = lo; e < hi; ++e){
      int s = s0[e];
      float2 v = *(const float2*)(x + (size_t)s*CDIM + lane*2);
      a0 += sc*v.x; a1 += sc*v.y;
    }
  }
  const u16* os[3]  = {o1, o2, o3};
  const int* rps[3] = {rp1, rp2, rp3};
#pragma unroll
  for (int li = 0; li < 3; ++li){
    const float sc = 1.f + repsg[1+li];
    int lo = rps[li][node], hi = rps[li][node+1];
    for (int e = lo; e < hi; ++e){
      u32 v = *(const u32*)(os[li] + (size_t)e*CDIM + lane*2);
      a0 += sc*bf2f(v & 0xffffu); a1 += sc*bf2f(v >> 16);
    }
  }
  *(u32*)(rcb + (size_t)node*CDIM + lane*2) = pack2(a0, a1);
}

// ---------------- final: out = mlp2((1+eps)*x + rc, fin_*)  (f32 out)
__global__ __launch_bounds__(256) void final_kernel(
    const float* __restrict__ x, const u16* __restrict__ rc,
    const u16* __restrict__ fw0T, const u16* __restrict__ fw1T,
    const float* __restrict__ fb0, const float* __restrict__ fb1,
    const float* __restrict__ epsg, float* __restrict__ outp)
{
  __shared__ __align__(16) u16 sW[CDIM*CDIM];
  __shared__ __align__(16) u16 sA[64*CDIM];
  const int tid  = threadIdx.x;
  const int wave = tid >> 6, lane = tid & 63;
  const int lr   = lane & 15, g = lane >> 4;
  const int r0   = blockIdx.x * 64;
  const float se = 1.0f + epsg[0];

  stage_w(fw0T, sW, tid);
  for (int c = tid; c < 64*16; c += 256){
    int r = c >> 4, ch = c & 15;
    int node = r0 + r;
    uint4 v = make_uint4(0,0,0,0);
    if (node < NNODES){
      const float4* px = (const float4*)(x + (size_t)node*CDIM + ch*8);
      float4 fa = px[0], fb = px[1];
      const u32* pr = (const u32*)(rc + (size_t)node*CDIM + ch*8);
      u32 r0v = pr[0], r1v = pr[1], r2v = pr[2], r3v = pr[3];
      v.x = pack2(se*fa.x + bf2f(r0v & 0xffffu), se*fa.y + bf2f(r0v >> 16));
      v.y = pack2(se*fa.z + bf2f(r1v & 0xffffu), se*fa.w + bf2f(r1v >> 16));
      v.z = pack2(se*fb.x + bf2f(r2v & 0xffffu), se*fb.y + bf2f(r2v >> 16));
      v.w = pack2(se*fb.z + bf2f(r3v & 0xffffu), se*fb.w + bf2f(r3v >> 16));
    }
    *(uint4*)&sA[(r*16 + (ch ^ (r & 7)))*8] = v;
  }
  __syncthreads();

  f32x4 acc[8];
#pragma unroll
  for (int ct = 0; ct < 8; ++ct) acc[ct] = (f32x4){0.f,0.f,0.f,0.f};
  gemm64(sA, sW, acc, wave, lane);
  __syncthreads();
#pragma unroll
  for (int ct = 0; ct < 8; ++ct){
    const int col = ct*16 + lr;
    const float bb = fb0[col];
#pragma unroll
    for (int q = 0; q < 4; ++q){
      const int r = wave*16 + g*4 + q;
      float t = acc[ct][q] + bb;
      t = t > 0.f ? t : 0.f;
      sA[swzi(r, col)] = f2bf(t);
    }
  }
  stage_w(fw1T, sW, tid);
  __syncthreads();
#pragma unroll
  for (int ct = 0; ct < 8; ++ct) acc[ct] = (f32x4){0.f,0.f,0.f,0.f};
  gemm64(sA, sW, acc, wave, lane);
#pragma unroll
  for (int ct = 0; ct < 8; ++ct){
    const int col = ct*16 + lr;
    const float bb = fb1[col];
#pragma unroll
    for (int q = 0; q < 4; ++q){
      const int r = wave*16 + g*4 + q;
      int node = r0 + r;
      if (node < NNODES) outp[(size_t)node*CDIM + col] = acc[ct][q] + bb;
    }
  }
}

extern "C" void kernel_launch(void* const* d_in, const int* in_sizes, int n_in,
                              void* d_out, int out_size, void* d_ws, size_t ws_size,
                              hipStream_t stream)
{
  const float* x   = (const float*)d_in[0];
  const int* n0    = (const int*)d_in[1];
  const int* n1    = (const int*)d_in[2];
  const int* a1    = (const int*)d_in[3];
  const int* n2    = (const int*)d_in[4];
  const int* a2    = (const int*)d_in[5];
  const int* n3    = (const int*)d_in[6];
  const int* a3    = (const int*)d_in[7];
  const float* emb = (const float*)d_in[8];
  const float* Wt  = (const float*)d_in[9];
  const float* bt  = (const float*)d_in[10];
  const float* w0  = (const float*)d_in[11];
  const float* b0  = (const float*)d_in[12];
  const float* w1  = (const float*)d_in[13];
  const float* b1  = (const float*)d_in[14];
  const float* ceps= (const float*)d_in[15];
  const float* reps= (const float*)d_in[16];
  const float* eps = (const float*)d_in[17];
  const float* fw0 = (const float*)d_in[18];
  const float* fb0 = (const float*)d_in[19];
  const float* fw1 = (const float*)d_in[20];
  const float* fb1 = (const float*)d_in[21];
  float* outp = (float*)d_out;

  char* w = (char*)d_ws;
  size_t off = 0;
  auto alloc = [&](size_t bytes) -> char* {
    char* p = w + off;
    off += (bytes + 255) & ~((size_t)255);
    return p;
  };
  u16* o1   = (u16*)alloc((size_t)ELEDGES*CDIM*2);
  u16* o2   = (u16*)alloc((size_t)ELEDGES*CDIM*2);
  u16* o3   = (u16*)alloc((size_t)ELEDGES*CDIM*2);
  u16* rcb  = (u16*)alloc((size_t)NNODES*CDIM*2);   // doubles as xb before gather_rc
  int* rp0  = (int*)alloc((size_t)(NNODES+1)*4);
  int* rp1  = (int*)alloc((size_t)(NNODES+1)*4);
  int* rp2  = (int*)alloc((size_t)(NNODES+1)*4);
  int* rp3  = (int*)alloc((size_t)(NNODES+1)*4);
  u16* WtT  = (u16*)alloc((size_t)3*CDIM*CDIM*2);
  u16* w0T  = (u16*)alloc((size_t)3*CDIM*CDIM*2);
  u16* w1T  = (u16*)alloc((size_t)3*CDIM*CDIM*2);
  u16* fw0T = (u16*)alloc((size_t)CDIM*CDIM*2);
  u16* fw1T = (u16*)alloc((size_t)CDIM*CDIM*2);
  float* eWt = (float*)alloc((size_t)3*3*CDIM*4);
  u16* xb   = rcb;   // alias: xb consumed by layer kernels, then rcb overwritten by gather_rc
  (void)ws_size; (void)in_sizes; (void)n_in; (void)out_size;

  prep_kernel<<<192, 256, 0, stream>>>(Wt, w0, w1, fw0, fw1, emb, bt,
                                       WtT, w0T, w1T, fw0T, fw1T, eWt);
  xb_kernel<<<(NNODES*CDIM/4 + 255)/256, 256, 0, stream>>>(x, xb);
  build_csr_kernel<<<(E0EDGES+255)/256, 256, 0, stream>>>(n0, E0EDGES, rp0);
  build_csr_kernel<<<(ELEDGES+255)/256, 256, 0, stream>>>(n1, ELEDGES, rp1);
  build_csr_kernel<<<(ELEDGES+255)/256, 256, 0, stream>>>(n2, ELEDGES, rp2);
  build_csr_kernel<<<(ELEDGES+255)/256, 256, 0, stream>>>(n3, ELEDGES, rp3);

  layer_kernel<1><<<ELEDGES/64, 512, 0, stream>>>(xb, n1, a1, WtT, w0T, w1T, eWt, b0, b1, ceps, o1);
  layer_kernel<2><<<ELEDGES/32, 512, 0, stream>>>(xb, n2, a2, WtT, w0T, w1T, eWt, b0, b1, ceps, o2);
  layer_kernel<3><<<ELEDGES/32, 512, 0, stream>>>(xb, n3, a3, WtT, w0T, w1T, eWt, b0, b1, ceps, o3);

  gather_rc_kernel<<<(NNODES+3)/4, 256, 0, stream>>>(x, n0 + E0EDGES, rp0, rp1, rp2, rp3,
                                                     o1, o2, o3, reps, rcb);
  final_kernel<<<(NNODES+63)/64, 256, 0, stream>>>(x, rcb, fw0T, fw1T, fb0, fb1, eps, outp);
}